// Round 2
// baseline (987.676 us; speedup 1.0000x reference)
//
#include <hip/hip_runtime.h>
#include <hip/hip_cooperative_groups.h>
#include <limits.h>

#define NUM_Q    4096
#define MAX_STEP 256
#define BATCH    64
#define TWOQ     8192   // 2*NUM_Q
#define ROWS     (BATCH * MAX_STEP)   // 16384
#define ITERS    32     // 32 iters of 64 lanes x float4 = 1 KB/iter, 32 KB/row

namespace cg = cooperative_groups;

__device__ __forceinline__ float bce(float p, float a) {
    // matches torch BCELoss: logs clamped at -100. logf(0) = -inf -> clamped.
    float lp  = fmaxf(logf(p), -100.0f);
    float l1p = fmaxf(log1pf(-p), -100.0f);
    return -(a * lp + (1.0f - a) * l1p);
}

// Single cooperative dispatch.
// Phase 1: one wave per (b,s) row of batch [B,S,2Q], early-exit ballot scan
//          for the one-hot index; lane 0 gathers pred[b,s-1,qid] into pw.
//          Grid-stride with s-flip on odd passes: a wave that drew a low-s
//          (padding-prone, full-32KB dependent-chain) row gets a high-s
//          (instant-hit) row next, capping the straggler chain.
// grid.sync()
// Phase 2: blocks 0..63, one per student: trim index i0, masked BCE sum,
//          tail term, atomicAdd into out[0] (zeroed pre-sync by one thread).
__global__ void __launch_bounds__(256) fused_kernel(
        const float* __restrict__ batch,
        const float* __restrict__ pred,
        const float* __restrict__ target_q,
        const float* __restrict__ target_label,
        int* __restrict__ qa,
        float* __restrict__ pw,
        float* __restrict__ out) {
    const int t     = threadIdx.x;
    const int lane  = t & 63;
    const int gwave = (int)((blockIdx.x * blockDim.x + t) >> 6);
    const int nwave = (int)((gridDim.x * blockDim.x) >> 6);  // multiple of 256

    if (blockIdx.x == 0 && t == 0) out[0] = 0.0f;  // ordered by grid.sync()

    // ---- phase 1: one-hot scan ----
    for (int base = gwave, pass = 0; base < ROWS; base += nwave, ++pass) {
        // odd passes flip s (low 8 bits). nwave is a multiple of 256 and
        // ROWS is a multiple of 256, so this is a bijection on the row set.
        const int row = (pass & 1) ? (base ^ (MAX_STEP - 1)) : base;
        const int s   = row & (MAX_STEP - 1);
        if (s == 0) continue;          // qa[b,0]/pw[b,0] never read in phase 2

        const float4* rp = (const float4*)(batch + (size_t)row * TWOQ);
        int found = -1;
        for (int it = 0; it < ITERS; ++it) {
            const float4 v = rp[it * 64 + lane];
            const float sum = v.x + v.y + v.z + v.w;          // 0.0 or 1.0
            const unsigned long long m = __ballot(sum > 0.0f); // wave-uniform
            if (m) {
                const int src = __ffsll(m) - 1;
                int idx = 0;
                if (lane == src) {
                    const int bidx = (it * 64 + lane) * 4;
                    idx = (v.x != 0.f) ? bidx
                        : (v.y != 0.f) ? bidx + 1
                        : (v.z != 0.f) ? bidx + 2
                                       : bidx + 3;
                }
                found = __shfl(idx, src);
                break;
            }
        }
        if (lane == 0) {
            qa[row] = found;
            float p = 0.0f;
            if (found >= 0) {
                const int b   = row >> 8;              // row / MAX_STEP
                const int qid = found & (NUM_Q - 1);
                p = pred[((size_t)b * MAX_STEP + (s - 1)) * NUM_Q + qid];
            }
            pw[row] = p;                               // 0.0 for padding rows
        }
    }

    cg::this_grid().sync();

    // ---- phase 2: loss, one block per student ----
    const int b = blockIdx.x;
    if (b >= BATCH) return;
    const int wid = t >> 6;
    const int SM1 = MAX_STEP - 1;  // 255

    __shared__ int   smin[4];
    __shared__ float ssum[4];

    // step s = t (covers 0..254), uses qa/pw[b, t+1] (all written: s>=1).
    int   idx = -1;
    float p   = 0.0f;
    if (t < SM1) {
        idx = qa[b * MAX_STEP + t + 1];
        p   = pw[b * MAX_STEP + t + 1];
    }

    // i0 = first s with p > 0 (pred >= 0.01 so valid gather => p > 0).
    // argmax of all-false -> 0.
    int cand = (t < SM1 && p > 0.0f) ? t : INT_MAX;
    #pragma unroll
    for (int off = 32; off > 0; off >>= 1)
        cand = min(cand, __shfl_down(cand, off));
    if (lane == 0) smin[wid] = cand;
    __syncthreads();
    int i0 = min(min(smin[0], smin[1]), min(smin[2], smin[3]));
    if (i0 == INT_MAX) i0 = 0;

    // seq_loss: sum BCE over masked steps s >= i0
    float v = 0.0f;
    if (t < SM1 && t >= i0) {
        const float a = (idx >= 0 && idx < NUM_Q) ? 1.0f : 0.0f;
        v = bce(p, a);   // padding rows: bce(0,0) == 0, matches reference
    }
    #pragma unroll
    for (int off = 32; off > 0; off >>= 1)
        v += __shfl_down(v, off);
    if (lane == 0) ssum[wid] = v;
    __syncthreads();

    if (t == 0) {
        const float tail = bce(target_q[b], target_label[b]);
        const float n = (float)(MAX_STEP - i0);  // (S-1) - i0 + 1
        atomicAdd(out, (ssum[0] + ssum[1] + ssum[2] + ssum[3] + tail) / n);
    }
}

extern "C" void kernel_launch(void* const* d_in, const int* in_sizes, int n_in,
                              void* d_out, int out_size, void* d_ws, size_t ws_size,
                              hipStream_t stream) {
    const float* pred         = (const float*)d_in[0];  // [B,S,Q]
    const float* target_q     = (const float*)d_in[1];  // [B,1]
    const float* batch        = (const float*)d_in[2];  // [B,S,2Q]
    const float* target_label = (const float*)d_in[3];  // [B]
    float* out = (float*)d_out;
    int*   qa  = (int*)d_ws;              // ROWS ints   = 64 KB
    float* pw  = (float*)(qa + ROWS);     // ROWS floats = 64 KB

    // Size the cooperative grid once: all blocks must be co-resident.
    static int nblk = 0;
    if (nblk == 0) {
        int bpc = 0;
        hipError_t e = hipOccupancyMaxActiveBlocksPerMultiprocessor(
            &bpc, fused_kernel, 256, 0);
        if (e != hipSuccess || bpc < 1) bpc = 1;
        int g = bpc * 256;                 // 256 CUs on MI355X
        if (g > ROWS / 4) g = ROWS / 4;    // >1 wave per row is useless
        g = (g / 64) * 64;                 // nwave multiple of 256 (s-flip bijection)
        if (g < 64) g = 64;                // phase 2 needs 64 blocks
        nblk = g;
    }

    void* args[] = { (void*)&batch, (void*)&pred, (void*)&target_q,
                     (void*)&target_label, (void*)&qa, (void*)&pw, (void*)&out };
    hipLaunchCooperativeKernel((const void*)fused_kernel, dim3(nblk), dim3(256),
                               args, 0, stream);
}

// Round 3
// 726.817 us; speedup vs baseline: 1.3589x; 1.3589x over previous
//
#include <hip/hip_runtime.h>
#include <limits.h>

#define NUM_Q    4096
#define MAX_STEP 256
#define BATCH    64
#define TWOQ     8192   // 2*NUM_Q
#define ROWS     (BATCH * MAX_STEP)   // 16384
#define ITERS    32     // 32 iters of 64 lanes x float4 = 1 KB per iter, 32 KB per row

// Kernel 1: ONE WAVE per (b,s) row of batch [B,S,2Q]. Scan for the single
// nonzero (one-hot) with early exit via wave ballot; values are exactly 0.0 or
// 1.0 so sum>0 detects a hit. qa[row] = idx in [0,8192) or -1 (padding row).
//
// NOTE (R2 post-mortem): do NOT fuse these two kernels with a grid-wide
// barrier. grid.sync() makes the makespan the WORST wave's serial
// dependent-load chain (and the spin traffic starves stragglers): measured
// 361 us fused vs ~52 us for this two-dispatch form (VALUBusy 1.2%,
// hbm 4.5% peak while 93% occupancy = everyone spinning at the barrier).
// Independent dispatches let slow scan waves retire last, fully overlapped.
//
//  - no speculative prefetch: on exit the prefetched 1 KB/row is pure waste
//    (~16 MB); 32 resident waves/CU x 1 KB in flight hides latency fine.
//  - rows with s==0 skipped: loss only reads qa[b, t+1], t<=254 (-1 MB).
//  - lane 0 gathers p = pred[b, s-1, qid] here (scattered 4B read over a
//    256 MB buffer) into pw, so kernel 2 only touches 128 KB of L2-hot ws.
//  - out-zeroing folded in (no memset dispatch).
__global__ void __launch_bounds__(256) find_onehot_kernel(
        const float* __restrict__ batch,
        const float* __restrict__ pred,
        int* __restrict__ qa,
        float* __restrict__ pw,
        float* __restrict__ out, int out_n) {
    const int gtid = blockIdx.x * blockDim.x + threadIdx.x;
    if (gtid < out_n) out[gtid] = 0.0f;   // replaces memset dispatch

    const int row  = gtid >> 6;        // global wave id = row
    const int lane = gtid & 63;
    if (row >= ROWS) return;
    const int s = row & (MAX_STEP - 1);
    if (s == 0) return;                // qa[b,0] never read by loss kernel

    const float4* rp = (const float4*)(batch + (size_t)row * TWOQ);

    int found = -1;
    for (int it = 0; it < ITERS; ++it) {
        const float4 v = rp[it * 64 + lane];
        const float sum = v.x + v.y + v.z + v.w;         // 0.0 or 1.0
        const unsigned long long m = __ballot(sum > 0.0f); // wave-uniform
        if (m) {
            const int src = __ffsll(m) - 1;
            int idx = 0;
            if (lane == src) {
                const int base = (it * 64 + lane) * 4;
                idx = (v.x != 0.f) ? base
                    : (v.y != 0.f) ? base + 1
                    : (v.z != 0.f) ? base + 2
                                   : base + 3;
            }
            found = __shfl(idx, src);
            break;
        }
    }

    if (lane == 0) {
        qa[row] = found;
        float p = 0.0f;
        if (found >= 0) {
            const int b   = row >> 8;              // row / MAX_STEP
            const int qid = found & (NUM_Q - 1);
            p = pred[((size_t)b * MAX_STEP + (s - 1)) * NUM_Q + qid];
        }
        pw[row] = p;                               // 0.0 for padding rows
    }
}

__device__ __forceinline__ float bce(float p, float a) {
    // matches torch BCELoss: logs clamped at -100. logf(0) = -inf -> clamped.
    float lp  = fmaxf(logf(p), -100.0f);
    float l1p = fmaxf(log1pf(-p), -100.0f);
    return -(a * lp + (1.0f - a) * l1p);
}

// Kernel 2: one block per student b. Reads only qa/pw from workspace (L2-hot).
// Finds trim index i0, sums BCE over s>=i0, adds tail term, divides by
// n = 256 - i0, atomically accumulates into out[0].
__global__ void __launch_bounds__(256) loss_kernel(
        const float* __restrict__ target_q,
        const float* __restrict__ target_label,
        const int* __restrict__ qa,
        const float* __restrict__ pw,
        float* __restrict__ out) {
    const int b    = blockIdx.x;
    const int t    = threadIdx.x;
    const int lane = t & 63;
    const int wid  = t >> 6;
    const int SM1  = MAX_STEP - 1;  // 255

    __shared__ int   smin[4];
    __shared__ float ssum[4];

    // step s = t (covers 0..254), uses qa/pw[b, t+1] (all written: s>=1).
    int   idx = -1;
    float p   = 0.0f;
    if (t < SM1) {
        idx = qa[b * MAX_STEP + t + 1];
        p   = pw[b * MAX_STEP + t + 1];
    }

    // i0 = first s with p > 0 (pred >= 0.01 so any valid gather gives p > 0).
    // argmax of all-false -> 0.
    int cand = (t < SM1 && p > 0.0f) ? t : INT_MAX;
    #pragma unroll
    for (int off = 32; off > 0; off >>= 1)
        cand = min(cand, __shfl_down(cand, off));
    if (lane == 0) smin[wid] = cand;
    __syncthreads();
    int i0 = min(min(smin[0], smin[1]), min(smin[2], smin[3]));
    if (i0 == INT_MAX) i0 = 0;

    // seq_loss: sum BCE over masked steps s >= i0
    float v = 0.0f;
    if (t < SM1 && t >= i0) {
        const float a = (idx >= 0 && idx < NUM_Q) ? 1.0f : 0.0f;
        v = bce(p, a);   // padding rows: bce(0,0) == 0, matches reference
    }
    #pragma unroll
    for (int off = 32; off > 0; off >>= 1)
        v += __shfl_down(v, off);
    if (lane == 0) ssum[wid] = v;
    __syncthreads();

    if (t == 0) {
        const float tail = bce(target_q[b], target_label[b]);
        const float n = (float)(MAX_STEP - i0);  // (S-1) - i0 + 1
        atomicAdd(out, (ssum[0] + ssum[1] + ssum[2] + ssum[3] + tail) / n);
    }
}

extern "C" void kernel_launch(void* const* d_in, const int* in_sizes, int n_in,
                              void* d_out, int out_size, void* d_ws, size_t ws_size,
                              hipStream_t stream) {
    const float* pred         = (const float*)d_in[0];  // [B,S,Q]
    const float* target_q     = (const float*)d_in[1];  // [B,1]
    const float* batch        = (const float*)d_in[2];  // [B,S,2Q]
    const float* target_label = (const float*)d_in[3];  // [B]
    float* out = (float*)d_out;
    int*   qa  = (int*)d_ws;              // ROWS ints   = 64 KB
    float* pw  = (float*)(qa + ROWS);     // ROWS floats = 64 KB

    // one wave per row: ROWS waves = ROWS*64 threads, 256-thread blocks
    find_onehot_kernel<<<(ROWS * 64) / 256, 256, 0, stream>>>(
        batch, pred, qa, pw, out, out_size);
    loss_kernel<<<BATCH, 256, 0, stream>>>(target_q, target_label, qa, pw, out);
}